// Round 4
// baseline (689.232 us; speedup 1.0000x reference)
//
#include <hip/hip_runtime.h>

// Batched complex QR (Householder, LAPACK clarfg/cgeqr2 convention).
// One batch element per wave; lane = matrix row (M=64 == wavefront size).
//
// v5 strategy:
//  * Round-3 post-mortem: VGPR_Count stayed 60 and occupancy 43.5%
//    (=3.5 waves/SIMD, ~146 unified regs) => arrays live in AGPRs with
//    v_accvgpr_read/write on every access (~2.3x VALU inflation).
//    __launch_bounds__(256,1) only sets MIN waves/EU; the allocator still
//    chased occupancy via AGPR storage. Fix: amdgpu_waves_per_eu(4,4)
//    caps the occupancy target at 4 waves/EU -> 128 arch-VGPR budget,
//    arrays live in VGPRs, no copies. (2,2) on the fp64 redo kernels.
//  * FP32 factorization with pure-VALU wave reductions (DPP-fused adds +
//    permlane16_swap + permlane32_swap). Q = A * R^-1 triangular solve
//    (readlane broadcasts, no reductions).
//  * Sign robustness: fp32 error in Re(alpha) ~3e-6 rms; batches with any
//    |Re(alpha_i)| < 2e-4 (~70 sigma margin, ~0.26% of batches) go onto a
//    compacted worklist and are redone in fp64 (pure-VALU reductions).

constexpr int Mrows = 64;
constexpr int Rcols = 16;

typedef int v2i __attribute__((ext_vector_type(2)));

#if defined(__has_builtin)
#if __has_builtin(__builtin_amdgcn_permlane16_swap)
#define USE_PL16 1
#else
#define USE_PL16 0
#endif
#if __has_builtin(__builtin_amdgcn_permlane32_swap)
#define USE_PL32 1
#else
#define USE_PL32 0
#endif
#else
#define USE_PL16 0
#define USE_PL32 0
#endif

// ---------------- fp32 wave-64 sum-broadcast (pure VALU) ----------------
template <int CTRL>
__device__ __forceinline__ float dpp_fadd(float v) {
  int s = __builtin_amdgcn_update_dpp(0, __float_as_int(v), CTRL, 0xF, 0xF, true);
  return v + __int_as_float(s);
}

__device__ __forceinline__ float wsum64f_fast(float v, int bpa) {
  v = dpp_fadd<0xB1>(v);   // quad_perm [1,0,3,2]  : + lane^1
  v = dpp_fadd<0x4E>(v);   // quad_perm [2,3,0,1]  : + lane^2
  v = dpp_fadd<0x141>(v);  // row_half_mirror      : fold 8-group
  v = dpp_fadd<0x140>(v);  // row_mirror           : fold 16-group
#if USE_PL16
  {
    v2i r = __builtin_amdgcn_permlane16_swap(__float_as_int(v), __float_as_int(v),
                                             false, false);
    v = __int_as_float(r[0]) + __int_as_float(r[1]);  // + lane^16
  }
#else
  v += __int_as_float(__builtin_amdgcn_ds_swizzle(__float_as_int(v), 0x401F));
#endif
#if USE_PL32
  {
    v2i r = __builtin_amdgcn_permlane32_swap(__float_as_int(v), __float_as_int(v),
                                             false, false);
    v = __int_as_float(r[0]) + __int_as_float(r[1]);  // + lane^32
  }
#else
  v += __int_as_float(__builtin_amdgcn_ds_bpermute(bpa, __float_as_int(v)));
#endif
  return v;
}

__device__ __forceinline__ float rdlane(float v, int srclane) {
  return __int_as_float(__builtin_amdgcn_readlane(__float_as_int(v), srclane));
}

// ---------------- fp64 wave-64 sum-broadcast (pure VALU) ----------------
template <int CTRL>
__device__ __forceinline__ double dpp_dadd(double v) {
  union { double d; int i[2]; } u, s;
  u.d = v;
  s.i[0] = __builtin_amdgcn_update_dpp(0, u.i[0], CTRL, 0xF, 0xF, true);
  s.i[1] = __builtin_amdgcn_update_dpp(0, u.i[1], CTRL, 0xF, 0xF, true);
  return v + s.d;
}

__device__ __forceinline__ double plswap16_add_d(double v) {
#if USE_PL16
  union { double d; int i[2]; } u, a, b;
  u.d = v;
  v2i rlo = __builtin_amdgcn_permlane16_swap(u.i[0], u.i[0], false, false);
  v2i rhi = __builtin_amdgcn_permlane16_swap(u.i[1], u.i[1], false, false);
  a.i[0] = rlo[0]; a.i[1] = rhi[0];
  b.i[0] = rlo[1]; b.i[1] = rhi[1];
  return a.d + b.d;
#else
  return v + __shfl_xor(v, 16, 64);
#endif
}

__device__ __forceinline__ double plswap32_add_d(double v) {
#if USE_PL32
  union { double d; int i[2]; } u, a, b;
  u.d = v;
  v2i rlo = __builtin_amdgcn_permlane32_swap(u.i[0], u.i[0], false, false);
  v2i rhi = __builtin_amdgcn_permlane32_swap(u.i[1], u.i[1], false, false);
  a.i[0] = rlo[0]; a.i[1] = rhi[0];
  b.i[0] = rlo[1]; b.i[1] = rhi[1];
  return a.d + b.d;
#else
  return v + __shfl_xor(v, 32, 64);
#endif
}

__device__ __forceinline__ double wsum64d_fast(double v) {
  v = dpp_dadd<0xB1>(v);
  v = dpp_dadd<0x4E>(v);
  v = dpp_dadd<0x141>(v);
  v = dpp_dadd<0x140>(v);
  v = plswap16_add_d(v);
  v = plswap32_add_d(v);
  return v;
}

__device__ __forceinline__ double rdlaned(double v, int srclane) {
  union { double d; int i[2]; } u, r;
  u.d = v;
  r.i[0] = __builtin_amdgcn_readlane(u.i[0], srclane);
  r.i[1] = __builtin_amdgcn_readlane(u.i[1], srclane);
  return r.d;
}

// =====================================================================
// Pass 1: FP32 factorization + Q = A R^-1 solve. Risky batches -> worklist.
// =====================================================================
__global__ __launch_bounds__(256)
__attribute__((amdgpu_waves_per_eu(4, 4)))
void qr_house_f32(
    const float* __restrict__ x, float* __restrict__ out,
    int* __restrict__ cnt, int* __restrict__ list,
    unsigned char* __restrict__ flags, int B) {
  const int lane = threadIdx.x & 63;
  const int wave = threadIdx.x >> 6;
  const int b = blockIdx.x * 4 + wave;
  if (b >= B) return;
  const int bpa = ((lane ^ 32) << 2);  // ds_bpermute fallback addr

  const float4* xp = reinterpret_cast<const float4*>(
      x + (size_t)b * (Mrows * Rcols * 2) + (size_t)lane * (Rcols * 2));
  float xr[Rcols], xi[Rcols];   // original A (becomes Q in the solve)
  float ar[Rcols], ai[Rcols];   // working copy -> R (upper) + reflectors
#pragma unroll
  for (int k = 0; k < Rcols / 2; ++k) {
    float4 t = xp[k];
    xr[2 * k] = t.x;  xi[2 * k] = t.y;
    xr[2 * k + 1] = t.z;  xi[2 * k + 1] = t.w;
  }
#pragma unroll
  for (int j = 0; j < Rcols; ++j) { ar[j] = xr[j]; ai[j] = xi[j]; }

  bool risky = false;

  // ---- cgeqr2 in fp32 (apply H_i^H = I - conj(tau) v v^H) ----
#pragma unroll
  for (int i = 0; i < Rcols; ++i) {
    float cr = ar[i], ci = ai[i];
    float sq = (lane > i) ? (cr * cr + ci * ci) : 0.0f;
    float xnorm2 = wsum64f_fast(sq, bpa);
    float alphr = rdlane(cr, i);
    float alphi = rdlane(ci, i);

    // Near-tie sign decision -> fp64 pass redoes this batch.
    // fp32 alpha error ~3e-6 rms; 2e-4 keeps ~70 sigma margin, ~0.26% flagged.
    risky = risky || (fabsf(alphr) < 2e-4f);

    float tr, ti;
    if (xnorm2 == 0.0f && alphi == 0.0f) {
      tr = 0.0f;  ti = 0.0f;
    } else {
      float nrm = __builtin_amdgcn_sqrtf(alphr * alphr + alphi * alphi + xnorm2);
      float beta = (alphr >= 0.0f) ? -nrm : nrm;  // -SIGN(nrm, alphr)
      float rb = __builtin_amdgcn_rcpf(beta);
      tr = (beta - alphr) * rb;
      ti = -alphi * rb;
      float dr = alphr - beta, di = alphi;
      float inv = __builtin_amdgcn_rcpf(dr * dr + di * di);
      float sr = dr * inv, si = -di * inv;
      if (lane > i) {  // v = x / (alpha - beta), stored below diagonal
        ar[i] = cr * sr - ci * si;
        ai[i] = cr * si + ci * sr;
      }
      if (lane == i) {  // R diagonal (real beta) for the solve
        ar[i] = beta;
        ai[i] = 0.0f;
      }
    }

    float vr = (lane == i) ? 1.0f : ((lane > i) ? ar[i] : 0.0f);
    float vi = (lane == i) ? 0.0f : ((lane > i) ? ai[i] : 0.0f);
    const float ctr = tr, cti = -ti;  // conj(tau)
#pragma unroll
    for (int j = i + 1; j < Rcols; ++j) {
      float pr = vr * ar[j] + vi * ai[j];
      float pi = vr * ai[j] - vi * ar[j];
      pr = wsum64f_fast(pr, bpa);
      pi = wsum64f_fast(pi, bpa);
      float wr = ctr * pr - cti * pi;
      float wi = ctr * pi + cti * pr;
      ar[j] -= wr * vr - wi * vi;
      ai[j] -= wr * vi + wi * vr;
    }
  }

  if (risky) {  // wave-uniform (alphr is broadcast)
    if (lane == 0) {
      if (cnt) {
        int idx = atomicAdd(cnt, 1);
        list[idx] = b;
      } else {
        flags[b] = 1;
      }
    }
    return;  // fp64 pass produces this batch's output
  }
  if (!cnt && lane == 0) flags[b] = 0;

  // ---- Q via triangular solve: Q[:,j] = (A[:,j] - sum_{k<j} Q[:,k] R[k,j]) / beta_j
#pragma unroll
  for (int j = 0; j < Rcols; ++j) {
    float wr = xr[j], wi = xi[j];
#pragma unroll
    for (int k = 0; k < j; ++k) {
      float rr = rdlane(ar[j], k);
      float ri = rdlane(ai[j], k);
      wr -= xr[k] * rr - xi[k] * ri;
      wi -= xr[k] * ri + xi[k] * rr;
    }
    float rb = __builtin_amdgcn_rcpf(rdlane(ar[j], j));  // beta_j is real
    xr[j] = wr * rb;
    xi[j] = wi * rb;
  }

  float4* op = reinterpret_cast<float4*>(
      out + (size_t)b * (Mrows * Rcols * 2) + (size_t)lane * (Rcols * 2));
#pragma unroll
  for (int k = 0; k < Rcols / 2; ++k) {
    op[k] = make_float4(xr[2 * k], xi[2 * k], xr[2 * k + 1], xi[2 * k + 1]);
  }
}

// =====================================================================
// FP64 redo: proven math, pure-VALU reductions, one batch per wave.
// =====================================================================
__device__ void qr_f64_one(const float* __restrict__ x,
                           float* __restrict__ out, int b, int lane, int bpa) {
  const float4* xp = reinterpret_cast<const float4*>(
      x + (size_t)b * (Mrows * Rcols * 2) + (size_t)lane * (Rcols * 2));
  double ar[Rcols], ai[Rcols];
#pragma unroll
  for (int k = 0; k < Rcols / 2; ++k) {
    float4 t = xp[k];
    ar[2 * k] = (double)t.x;
    ai[2 * k] = (double)t.y;
    ar[2 * k + 1] = (double)t.z;
    ai[2 * k + 1] = (double)t.w;
  }

  double taur[Rcols], taui[Rcols];

#pragma unroll
  for (int i = 0; i < Rcols; ++i) {
    double cr = ar[i], ci = ai[i];
    double sq = (lane > i) ? (cr * cr + ci * ci) : 0.0;
    double xnorm2 = wsum64d_fast(sq);
    double alphr = rdlaned(cr, i);
    double alphi = rdlaned(ci, i);

    double tr, ti;
    if (xnorm2 == 0.0 && alphi == 0.0) {
      tr = 0.0;
      ti = 0.0;
    } else {
      double nrm = sqrt(alphr * alphr + alphi * alphi + xnorm2);
      double beta = (alphr >= 0.0) ? -nrm : nrm;
      double rb = 1.0 / beta;
      tr = (beta - alphr) * rb;
      ti = -alphi * rb;
      double dr = alphr - beta, di = alphi;
      double inv = 1.0 / (dr * dr + di * di);
      double sr = dr * inv, si = -di * inv;
      if (lane > i) {
        double nr = cr * sr - ci * si;
        double ni = cr * si + ci * sr;
        ar[i] = nr;
        ai[i] = ni;
      }
    }
    taur[i] = tr;
    taui[i] = ti;

    double vr = (lane == i) ? 1.0 : ((lane > i) ? ar[i] : 0.0);
    double vi = (lane == i) ? 0.0 : ((lane > i) ? ai[i] : 0.0);
    const double ctr = tr, cti = -ti;
#pragma unroll
    for (int j = i + 1; j < Rcols; ++j) {
      double pr = vr * ar[j] + vi * ai[j];
      double pi = vr * ai[j] - vi * ar[j];
      pr = wsum64d_fast(pr);
      pi = wsum64d_fast(pi);
      double wr = ctr * pr - cti * pi;
      double wi = ctr * pi + cti * pr;
      ar[j] -= wr * vr - wi * vi;
      ai[j] -= wr * vi + wi * vr;
    }
  }

  float vfr[Rcols], vfi[Rcols], tfr[Rcols], tfi[Rcols];
#pragma unroll
  for (int i = 0; i < Rcols; ++i) {
    vfr[i] = (lane == i) ? 1.0f : ((lane > i) ? (float)ar[i] : 0.0f);
    vfi[i] = (lane == i) ? 0.0f : ((lane > i) ? (float)ai[i] : 0.0f);
    tfr[i] = (float)taur[i];
    tfi[i] = (float)taui[i];
  }

  float qre[Rcols], qim[Rcols];
#pragma unroll
  for (int i = Rcols - 1; i >= 0; --i) {
    const float tr = tfr[i], ti = tfi[i];
    const float vr = vfr[i], vi = vfi[i];
#pragma unroll
    for (int j = i + 1; j < Rcols; ++j) {
      float pr = vr * qre[j] + vi * qim[j];
      float pi = vr * qim[j] - vi * qre[j];
      pr = wsum64f_fast(pr, bpa);
      pi = wsum64f_fast(pi, bpa);
      float wr = tr * pr - ti * pi;
      float wi = tr * pi + ti * pr;
      qre[j] -= wr * vr - wi * vi;
      qim[j] -= wr * vi + wi * vr;
    }
    float dr = -(tr * vr - ti * vi);
    float di = -(tr * vi + ti * vr);
    if (lane == i) {
      dr = 1.0f - tr;
      di = -ti;
    }
    if (lane < i) {
      dr = 0.0f;
      di = 0.0f;
    }
    qre[i] = dr;
    qim[i] = di;
  }

  float4* op = reinterpret_cast<float4*>(
      out + (size_t)b * (Mrows * Rcols * 2) + (size_t)lane * (Rcols * 2));
#pragma unroll
  for (int k = 0; k < Rcols / 2; ++k) {
    op[k] = make_float4(qre[2 * k], qim[2 * k], qre[2 * k + 1], qim[2 * k + 1]);
  }
}

// Pass 2 (worklist mode): 2048 waves grid-stride over the compacted list.
__global__ __launch_bounds__(256)
__attribute__((amdgpu_waves_per_eu(2, 2)))
void qr_house_f64_list(
    const float* __restrict__ x, float* __restrict__ out,
    const int* __restrict__ cnt, const int* __restrict__ list) {
  const int lane = threadIdx.x & 63;
  const int bpa = ((lane ^ 32) << 2);
  const int widx = blockIdx.x * 4 + (threadIdx.x >> 6);
  const int n = *cnt;
  for (int w = widx; w < n; w += 2048) {
    qr_f64_one(x, out, list[w], lane, bpa);
  }
}

// Pass 2 (flags fallback / full fallback).
__global__ __launch_bounds__(256)
__attribute__((amdgpu_waves_per_eu(2, 2)))
void qr_house_f64_flags(
    const float* __restrict__ x, float* __restrict__ out,
    const unsigned char* __restrict__ flags, int B) {
  const int lane = threadIdx.x & 63;
  const int bpa = ((lane ^ 32) << 2);
  const int wave = threadIdx.x >> 6;
  const int b = blockIdx.x * 4 + wave;
  if (b >= B) return;
  if (flags && flags[b] == 0) return;
  qr_f64_one(x, out, b, lane, bpa);
}

extern "C" void kernel_launch(void* const* d_in, const int* in_sizes, int n_in,
                              void* d_out, int out_size, void* d_ws,
                              size_t ws_size, hipStream_t stream) {
  const float* x = (const float*)d_in[0];
  float* out = (float*)d_out;
  const int B = in_sizes[0] / (Mrows * Rcols * 2);
  dim3 block(256);  // 4 waves -> 4 batch elements per block
  dim3 grid((B + 3) / 4);

  const size_t need_list = 16 + (size_t)B * sizeof(int);
  if (d_ws && ws_size >= need_list) {
    int* cnt = (int*)d_ws;
    int* list = (int*)d_ws + 4;  // 16-byte offset
    hipMemsetAsync(d_ws, 0, 16, stream);  // zero the worklist counter
    qr_house_f32<<<grid, block, 0, stream>>>(x, out, cnt, list, nullptr, B);
    qr_house_f64_list<<<dim3(512), block, 0, stream>>>(x, out, cnt, list);
  } else if (d_ws && ws_size >= (size_t)B) {
    unsigned char* flags = (unsigned char*)d_ws;
    qr_house_f32<<<grid, block, 0, stream>>>(x, out, nullptr, nullptr, flags, B);
    qr_house_f64_flags<<<grid, block, 0, stream>>>(x, out, flags, B);
  } else {
    qr_house_f64_flags<<<grid, block, 0, stream>>>(x, out, nullptr, B);
  }
}

// Round 6
// 656.589 us; speedup vs baseline: 1.0497x; 1.0497x over previous
//
#include <hip/hip_runtime.h>

// Batched complex QR (Householder, LAPACK clarfg/cgeqr2 convention).
// One batch element per wave; lane = matrix row (M=64 == wavefront size).
//
// v7 strategy:
//  * Round-5 post-mortem: v6's inline-asm v_add_f32_dpp corrupted the
//    reductions — VALU-write -> DPP-read needs 2 wait states (ISA manual
//    "manually inserted NOPs"); the compiler inserts s_nop for builtin-emitted
//    DPP but cannot see inside inline asm. FAILED absmax 0.898.
//    Fix: revert reductions to the PROVEN builtin update_dpp + permlane-swap
//    path (passed rounds 3-5). The builtin path's extra instruction slots are
//    partly mandatory hazard nops, not removable overhead.
//  * Kept from v6 (math identical to v5, which passed):
//    - single fused dispatch: no workspace, no memset, no second launch
//      (pass-2 machinery cost ~310us total in rounds 3-4);
//    - triangular solve Q = A R^-1 interleaved into the factorization
//      (column i of R is final right after reflector i);
//    - risky waves (any |Re(alpha_i)| < 2e-4; fp32 alpha error ~3e-6 rms,
//      ~66 sigma margin, ~0.26% of waves) redo their batch inline in fp64
//      via a wave-uniform branch.

constexpr int Mrows = 64;
constexpr int Rcols = 16;

typedef int v2i __attribute__((ext_vector_type(2)));

#if defined(__has_builtin)
#if __has_builtin(__builtin_amdgcn_permlane16_swap)
#define USE_PL16 1
#else
#define USE_PL16 0
#endif
#if __has_builtin(__builtin_amdgcn_permlane32_swap)
#define USE_PL32 1
#else
#define USE_PL32 0
#endif
#else
#define USE_PL16 0
#define USE_PL32 0
#endif

// ---------------- fp32 wave-64 sum-broadcast (pure VALU, proven) ----------------
template <int CTRL>
__device__ __forceinline__ float dpp_fadd(float v) {
  int s = __builtin_amdgcn_update_dpp(0, __float_as_int(v), CTRL, 0xF, 0xF, true);
  return v + __int_as_float(s);
}

__device__ __forceinline__ float wsum64f_fast(float v, int bpa) {
  v = dpp_fadd<0xB1>(v);   // quad_perm [1,0,3,2]  : + lane^1
  v = dpp_fadd<0x4E>(v);   // quad_perm [2,3,0,1]  : + lane^2
  v = dpp_fadd<0x141>(v);  // row_half_mirror      : fold 8-group
  v = dpp_fadd<0x140>(v);  // row_mirror           : fold 16-group
#if USE_PL16
  {
    v2i r = __builtin_amdgcn_permlane16_swap(__float_as_int(v), __float_as_int(v),
                                             false, false);
    v = __int_as_float(r[0]) + __int_as_float(r[1]);  // + lane^16
  }
#else
  v += __int_as_float(__builtin_amdgcn_ds_swizzle(__float_as_int(v), 0x401F));
#endif
#if USE_PL32
  {
    v2i r = __builtin_amdgcn_permlane32_swap(__float_as_int(v), __float_as_int(v),
                                             false, false);
    v = __int_as_float(r[0]) + __int_as_float(r[1]);  // + lane^32
  }
#else
  v += __int_as_float(__builtin_amdgcn_ds_bpermute(bpa, __float_as_int(v)));
#endif
  return v;
}

__device__ __forceinline__ float rdlane(float v, int srclane) {
  return __int_as_float(__builtin_amdgcn_readlane(__float_as_int(v), srclane));
}

// ---------------- fp64 wave-64 sum-broadcast (pure VALU, proven) ----------------
template <int CTRL>
__device__ __forceinline__ double dpp_dadd(double v) {
  union { double d; int i[2]; } u, s;
  u.d = v;
  s.i[0] = __builtin_amdgcn_update_dpp(0, u.i[0], CTRL, 0xF, 0xF, true);
  s.i[1] = __builtin_amdgcn_update_dpp(0, u.i[1], CTRL, 0xF, 0xF, true);
  return v + s.d;
}

__device__ __forceinline__ double plswap16_add_d(double v) {
#if USE_PL16
  union { double d; int i[2]; } u, a, b;
  u.d = v;
  v2i rlo = __builtin_amdgcn_permlane16_swap(u.i[0], u.i[0], false, false);
  v2i rhi = __builtin_amdgcn_permlane16_swap(u.i[1], u.i[1], false, false);
  a.i[0] = rlo[0]; a.i[1] = rhi[0];
  b.i[0] = rlo[1]; b.i[1] = rhi[1];
  return a.d + b.d;
#else
  return v + __shfl_xor(v, 16, 64);
#endif
}

__device__ __forceinline__ double plswap32_add_d(double v) {
#if USE_PL32
  union { double d; int i[2]; } u, a, b;
  u.d = v;
  v2i rlo = __builtin_amdgcn_permlane32_swap(u.i[0], u.i[0], false, false);
  v2i rhi = __builtin_amdgcn_permlane32_swap(u.i[1], u.i[1], false, false);
  a.i[0] = rlo[0]; a.i[1] = rhi[0];
  b.i[0] = rlo[1]; b.i[1] = rhi[1];
  return a.d + b.d;
#else
  return v + __shfl_xor(v, 32, 64);
#endif
}

__device__ __forceinline__ double wsum64d_fast(double v) {
  v = dpp_dadd<0xB1>(v);
  v = dpp_dadd<0x4E>(v);
  v = dpp_dadd<0x141>(v);
  v = dpp_dadd<0x140>(v);
  v = plswap16_add_d(v);
  v = plswap32_add_d(v);
  return v;
}

__device__ __forceinline__ double rdlaned(double v, int srclane) {
  union { double d; int i[2]; } u, r;
  u.d = v;
  r.i[0] = __builtin_amdgcn_readlane(u.i[0], srclane);
  r.i[1] = __builtin_amdgcn_readlane(u.i[1], srclane);
  return r.d;
}

// =====================================================================
// FP64 redo (rare path, ~0.26% of waves): same solve-fused algorithm,
// full fp64. Sign decisions here match the float64 reference exactly.
// =====================================================================
__device__ void qr_f64_fused(const float* __restrict__ x,
                             float* __restrict__ out, int b, int lane) {
  const float4* xp = reinterpret_cast<const float4*>(
      x + (size_t)b * (Mrows * Rcols * 2) + (size_t)lane * (Rcols * 2));
  double xr[Rcols], xi[Rcols], ar[Rcols], ai[Rcols];
#pragma unroll
  for (int k = 0; k < Rcols / 2; ++k) {
    float4 t = xp[k];
    xr[2 * k] = (double)t.x;      xi[2 * k] = (double)t.y;
    xr[2 * k + 1] = (double)t.z;  xi[2 * k + 1] = (double)t.w;
  }
#pragma unroll
  for (int j = 0; j < Rcols; ++j) { ar[j] = xr[j]; ai[j] = xi[j]; }

#pragma unroll
  for (int i = 0; i < Rcols; ++i) {
    double cr = ar[i], ci = ai[i];
    double sq = (lane > i) ? (cr * cr + ci * ci) : 0.0;
    double xnorm2 = wsum64d_fast(sq);
    double alphr = rdlaned(cr, i);
    double alphi = rdlaned(ci, i);

    double tr, ti;
    if (xnorm2 == 0.0 && alphi == 0.0) {
      tr = 0.0;  ti = 0.0;  // column reduced; diagonal stays alpha (real)
    } else {
      double nrm = sqrt(alphr * alphr + alphi * alphi + xnorm2);
      double beta = (alphr >= 0.0) ? -nrm : nrm;  // -SIGN(nrm, alphr)
      double rb = 1.0 / beta;
      tr = (beta - alphr) * rb;
      ti = -alphi * rb;
      double dr = alphr - beta, di = alphi;
      double inv = 1.0 / (dr * dr + di * di);
      double sr = dr * inv, si = -di * inv;
      if (lane > i) {
        double nr = cr * sr - ci * si;
        double ni = cr * si + ci * sr;
        ar[i] = nr;
        ai[i] = ni;
      }
      if (lane == i) { ar[i] = beta; ai[i] = 0.0; }
    }

    double vr = (lane == i) ? 1.0 : ((lane > i) ? ar[i] : 0.0);
    double vi = (lane == i) ? 0.0 : ((lane > i) ? ai[i] : 0.0);
    const double ctr = tr, cti = -ti;  // conj(tau)
#pragma unroll
    for (int j = i + 1; j < Rcols; ++j) {
      double pr = fma(vr, ar[j], vi * ai[j]);
      double pi = fma(vr, ai[j], -(vi * ar[j]));
      pr = wsum64d_fast(pr);
      pi = wsum64d_fast(pi);
      double wr = fma(ctr, pr, -(cti * pi));
      double wi = fma(ctr, pi, cti * pr);
      ar[j] = fma(-wr, vr, fma(wi, vi, ar[j]));
      ai[j] = fma(-wr, vi, fma(-wi, vr, ai[j]));
    }

    // Solve column i: q_i = (a_i - sum_{k<i} q_k R[k,i]) / beta_i
    double swr = xr[i], swi = xi[i];
#pragma unroll
    for (int k = 0; k < Rcols; ++k) {
      if (k >= i) break;
      double rr = rdlaned(ar[i], k);
      double ri = rdlaned(ai[i], k);
      swr = fma(-xr[k], rr, fma(xi[k], ri, swr));
      swi = fma(-xr[k], ri, fma(-xi[k], rr, swi));
    }
    double rbd = 1.0 / rdlaned(ar[i], i);  // beta_i is real
    xr[i] = swr * rbd;
    xi[i] = swi * rbd;
  }

  float4* op = reinterpret_cast<float4*>(
      out + (size_t)b * (Mrows * Rcols * 2) + (size_t)lane * (Rcols * 2));
#pragma unroll
  for (int k = 0; k < Rcols / 2; ++k) {
    op[k] = make_float4((float)xr[2 * k], (float)xi[2 * k],
                        (float)xr[2 * k + 1], (float)xi[2 * k + 1]);
  }
}

// =====================================================================
// Fused single-dispatch kernel: FP32 factorization + interleaved solve;
// risky waves (near-tie sign decision) redo their batch in fp64 inline.
// =====================================================================
__global__ __launch_bounds__(256)
__attribute__((amdgpu_waves_per_eu(3)))
void qr_fused(const float* __restrict__ x, float* __restrict__ out, int B) {
  const int lane = threadIdx.x & 63;
  const int wave = threadIdx.x >> 6;
  const int b = blockIdx.x * 4 + wave;
  if (b >= B) return;
  const int bpa = ((lane ^ 32) << 2);  // ds_bpermute fallback addr

  const float4* xp = reinterpret_cast<const float4*>(
      x + (size_t)b * (Mrows * Rcols * 2) + (size_t)lane * (Rcols * 2));
  float xr[Rcols], xi[Rcols];   // original A -> becomes Q column-by-column
  float ar[Rcols], ai[Rcols];   // working copy -> R (upper) + reflectors
#pragma unroll
  for (int k = 0; k < Rcols / 2; ++k) {
    float4 t = xp[k];
    xr[2 * k] = t.x;  xi[2 * k] = t.y;
    xr[2 * k + 1] = t.z;  xi[2 * k + 1] = t.w;
  }
#pragma unroll
  for (int j = 0; j < Rcols; ++j) { ar[j] = xr[j]; ai[j] = xi[j]; }

  bool risky = false;

#pragma unroll
  for (int i = 0; i < Rcols; ++i) {
    // ---- clarfg on column i ----
    float cr = ar[i], ci = ai[i];
    float sq = (lane > i) ? fmaf(cr, cr, ci * ci) : 0.0f;
    float xnorm2 = wsum64f_fast(sq, bpa);
    float alphr = rdlane(cr, i);
    float alphi = rdlane(ci, i);

    // Near-tie sign decision -> this wave redoes its batch in fp64.
    risky = risky || (fabsf(alphr) < 2e-4f);

    float tr, ti;
    if (xnorm2 == 0.0f && alphi == 0.0f) {
      tr = 0.0f;  ti = 0.0f;  // column reduced; diagonal stays alpha (real)
    } else {
      float nrm = __builtin_amdgcn_sqrtf(
          fmaf(alphr, alphr, fmaf(alphi, alphi, xnorm2)));
      float beta = (alphr >= 0.0f) ? -nrm : nrm;  // -SIGN(nrm, alphr)
      float rb = __builtin_amdgcn_rcpf(beta);
      tr = (beta - alphr) * rb;
      ti = -alphi * rb;
      float dr = alphr - beta, di = alphi;
      float inv = __builtin_amdgcn_rcpf(fmaf(dr, dr, di * di));
      float sr = dr * inv, si = -di * inv;
      if (lane > i) {  // v = x / (alpha - beta), stored below diagonal
        float nr = fmaf(cr, sr, -(ci * si));
        float ni = fmaf(cr, si, ci * sr);
        ar[i] = nr;
        ai[i] = ni;
      }
      if (lane == i) { ar[i] = beta; ai[i] = 0.0f; }  // R diagonal (real)
    }

    // ---- apply H_i^H to trailing columns ----
    float vr = (lane == i) ? 1.0f : ((lane > i) ? ar[i] : 0.0f);
    float vi = (lane == i) ? 0.0f : ((lane > i) ? ai[i] : 0.0f);
    const float ctr = tr, cti = -ti;  // conj(tau)
#pragma unroll
    for (int j = i + 1; j < Rcols; ++j) {
      float pr = fmaf(vr, ar[j], vi * ai[j]);
      float pi = fmaf(vr, ai[j], -(vi * ar[j]));
      pr = wsum64f_fast(pr, bpa);
      pi = wsum64f_fast(pi, bpa);
      float wr = fmaf(ctr, pr, -(cti * pi));
      float wi = fmaf(ctr, pi, cti * pr);
      ar[j] = fmaf(-wr, vr, fmaf(wi, vi, ar[j]));
      ai[j] = fmaf(-wr, vi, fmaf(-wi, vr, ai[j]));
    }

    // ---- solve column i: q_i = (a_i - sum_{k<i} q_k R[k,i]) / beta_i ----
    // R[k,i] lives in lane k of ar[i]/ai[i]; ar[i]/ai[i] dead afterwards.
    float swr = xr[i], swi = xi[i];
#pragma unroll
    for (int k = 0; k < Rcols; ++k) {
      if (k >= i) break;
      float rr = rdlane(ar[i], k);
      float ri = rdlane(ai[i], k);
      swr = fmaf(-xr[k], rr, fmaf(xi[k], ri, swr));
      swi = fmaf(-xr[k], ri, fmaf(-xi[k], rr, swi));
    }
    float rb = __builtin_amdgcn_rcpf(rdlane(ar[i], i));  // beta_i is real
    xr[i] = swr * rb;
    xi[i] = swi * rb;
  }

  if (risky) {  // wave-uniform branch (~0.26% of waves)
    qr_f64_fused(x, out, b, lane);
    return;
  }

  float4* op = reinterpret_cast<float4*>(
      out + (size_t)b * (Mrows * Rcols * 2) + (size_t)lane * (Rcols * 2));
#pragma unroll
  for (int k = 0; k < Rcols / 2; ++k) {
    op[k] = make_float4(xr[2 * k], xi[2 * k], xr[2 * k + 1], xi[2 * k + 1]);
  }
}

extern "C" void kernel_launch(void* const* d_in, const int* in_sizes, int n_in,
                              void* d_out, int out_size, void* d_ws,
                              size_t ws_size, hipStream_t stream) {
  const float* x = (const float*)d_in[0];
  float* out = (float*)d_out;
  const int B = in_sizes[0] / (Mrows * Rcols * 2);
  dim3 block(256);  // 4 waves -> 4 batch elements per block
  dim3 grid((B + 3) / 4);
  qr_fused<<<grid, block, 0, stream>>>(x, out, B);
}

// Round 7
// 640.194 us; speedup vs baseline: 1.0766x; 1.0256x over previous
//
#include <hip/hip_runtime.h>

// Batched complex QR (Householder, LAPACK clarfg/cgeqr2 convention).
// One batch element per wave; lane = matrix row (M=64 == wavefront size).
//
// v8 strategy:
//  * Round-6 post-mortem: issue-bound at ~12.6k VALU slots/wave. Largest
//    modeled overhead: each permlane16/32_swap builtin returns 2 results ->
//    compiler emits preserving copies (~2k slots/wave across 512 swaps),
//    and the butterfly computes a per-lane broadcast although every
//    consumer of the sum is wave-uniform.
//    Fix: canonical GCN reduction ending — 4 proven in-row DPP stages,
//    then ROW_BCAST15 (rm 0xa) + ROW_BCAST31 (rm 0xc) + readlane(63).
//    Sum returns as a uniform scalar (SGPR-resident); tau/beta/w become
//    scalar operands (<=1 SGPR per fma — legal).
//  * Everything else unchanged from v7 (proven): single fused dispatch,
//    FP32 factorization + interleaved triangular solve Q = A R^-1,
//    risky waves (any |Re(alpha_i)| < 2e-4, ~0.26%) redo inline in fp64.

constexpr int Mrows = 64;
constexpr int Rcols = 16;

// ---------------- DPP sum stage: v += dpp(v), masked rows keep v ----------------
// update_dpp(old=0, ...) => lanes not written by the DPP pattern contribute 0.
template <int CTRL, int RM>
__device__ __forceinline__ float dpp_fadd(float v) {
  int s = __builtin_amdgcn_update_dpp(0, __float_as_int(v), CTRL, RM, 0xF, true);
  return v + __int_as_float(s);
}

__device__ __forceinline__ float rdlane(float v, int srclane) {
  return __int_as_float(__builtin_amdgcn_readlane(__float_as_int(v), srclane));
}

// Wave-64 sum, result returned as a wave-uniform scalar.
// Stages 1-4: in-row butterfly (proven since v3). Stage 5: row_bcast15
// (row1+=row0, row3+=row2; rm 0xa). Stage 6: row_bcast31 (rows2,3 += lane31
// = S0+S1; rm 0xc) -> lane 63 holds the total. readlane(63) broadcasts.
__device__ __forceinline__ float wsum64f_fast(float v) {
  v = dpp_fadd<0xB1, 0xF>(v);   // quad_perm [1,0,3,2] : + lane^1
  v = dpp_fadd<0x4E, 0xF>(v);   // quad_perm [2,3,0,1] : + lane^2
  v = dpp_fadd<0x141, 0xF>(v);  // row_half_mirror     : fold 8-group
  v = dpp_fadd<0x140, 0xF>(v);  // row_mirror          : fold 16-group
  v = dpp_fadd<0x142, 0xA>(v);  // row_bcast15         : rows 1,3 accumulate
  v = dpp_fadd<0x143, 0xC>(v);  // row_bcast31         : lane 63 = total
  return rdlane(v, 63);
}

// ---------------- fp64 variants (two 32-bit halves, proven pattern) ----------------
template <int CTRL, int RM>
__device__ __forceinline__ double dpp_dadd(double v) {
  union { double d; int i[2]; } u, s;
  u.d = v;
  s.i[0] = __builtin_amdgcn_update_dpp(0, u.i[0], CTRL, RM, 0xF, true);
  s.i[1] = __builtin_amdgcn_update_dpp(0, u.i[1], CTRL, RM, 0xF, true);
  return v + s.d;
}

__device__ __forceinline__ double rdlaned(double v, int srclane) {
  union { double d; int i[2]; } u, r;
  u.d = v;
  r.i[0] = __builtin_amdgcn_readlane(u.i[0], srclane);
  r.i[1] = __builtin_amdgcn_readlane(u.i[1], srclane);
  return r.d;
}

__device__ __forceinline__ double wsum64d_fast(double v) {
  v = dpp_dadd<0xB1, 0xF>(v);
  v = dpp_dadd<0x4E, 0xF>(v);
  v = dpp_dadd<0x141, 0xF>(v);
  v = dpp_dadd<0x140, 0xF>(v);
  v = dpp_dadd<0x142, 0xA>(v);
  v = dpp_dadd<0x143, 0xC>(v);
  return rdlaned(v, 63);
}

// =====================================================================
// FP64 redo (rare path, ~0.26% of waves): same solve-fused algorithm,
// full fp64. Sign decisions here match the float64 reference exactly.
// =====================================================================
__device__ void qr_f64_fused(const float* __restrict__ x,
                             float* __restrict__ out, int b, int lane) {
  const float4* xp = reinterpret_cast<const float4*>(
      x + (size_t)b * (Mrows * Rcols * 2) + (size_t)lane * (Rcols * 2));
  double xr[Rcols], xi[Rcols], ar[Rcols], ai[Rcols];
#pragma unroll
  for (int k = 0; k < Rcols / 2; ++k) {
    float4 t = xp[k];
    xr[2 * k] = (double)t.x;      xi[2 * k] = (double)t.y;
    xr[2 * k + 1] = (double)t.z;  xi[2 * k + 1] = (double)t.w;
  }
#pragma unroll
  for (int j = 0; j < Rcols; ++j) { ar[j] = xr[j]; ai[j] = xi[j]; }

#pragma unroll
  for (int i = 0; i < Rcols; ++i) {
    double cr = ar[i], ci = ai[i];
    double sq = (lane > i) ? (cr * cr + ci * ci) : 0.0;
    double xnorm2 = wsum64d_fast(sq);
    double alphr = rdlaned(cr, i);
    double alphi = rdlaned(ci, i);

    double tr, ti;
    if (xnorm2 == 0.0 && alphi == 0.0) {
      tr = 0.0;  ti = 0.0;  // column reduced; diagonal stays alpha (real)
    } else {
      double nrm = sqrt(alphr * alphr + alphi * alphi + xnorm2);
      double beta = (alphr >= 0.0) ? -nrm : nrm;  // -SIGN(nrm, alphr)
      double rb = 1.0 / beta;
      tr = (beta - alphr) * rb;
      ti = -alphi * rb;
      double dr = alphr - beta, di = alphi;
      double inv = 1.0 / (dr * dr + di * di);
      double sr = dr * inv, si = -di * inv;
      if (lane > i) {
        double nr = cr * sr - ci * si;
        double ni = cr * si + ci * sr;
        ar[i] = nr;
        ai[i] = ni;
      }
      if (lane == i) { ar[i] = beta; ai[i] = 0.0; }
    }

    double vr = (lane == i) ? 1.0 : ((lane > i) ? ar[i] : 0.0);
    double vi = (lane == i) ? 0.0 : ((lane > i) ? ai[i] : 0.0);
    const double ctr = tr, cti = -ti;  // conj(tau)
#pragma unroll
    for (int j = i + 1; j < Rcols; ++j) {
      double pr = fma(vr, ar[j], vi * ai[j]);
      double pi = fma(vr, ai[j], -(vi * ar[j]));
      pr = wsum64d_fast(pr);
      pi = wsum64d_fast(pi);
      double wr = fma(ctr, pr, -(cti * pi));
      double wi = fma(ctr, pi, cti * pr);
      ar[j] = fma(-wr, vr, fma(wi, vi, ar[j]));
      ai[j] = fma(-wr, vi, fma(-wi, vr, ai[j]));
    }

    // Solve column i: q_i = (a_i - sum_{k<i} q_k R[k,i]) / beta_i
    double swr = xr[i], swi = xi[i];
#pragma unroll
    for (int k = 0; k < Rcols; ++k) {
      if (k >= i) break;
      double rr = rdlaned(ar[i], k);
      double ri = rdlaned(ai[i], k);
      swr = fma(-xr[k], rr, fma(xi[k], ri, swr));
      swi = fma(-xr[k], ri, fma(-xi[k], rr, swi));
    }
    double rbd = 1.0 / rdlaned(ar[i], i);  // beta_i is real
    xr[i] = swr * rbd;
    xi[i] = swi * rbd;
  }

  float4* op = reinterpret_cast<float4*>(
      out + (size_t)b * (Mrows * Rcols * 2) + (size_t)lane * (Rcols * 2));
#pragma unroll
  for (int k = 0; k < Rcols / 2; ++k) {
    op[k] = make_float4((float)xr[2 * k], (float)xi[2 * k],
                        (float)xr[2 * k + 1], (float)xi[2 * k + 1]);
  }
}

// =====================================================================
// Fused single-dispatch kernel: FP32 factorization + interleaved solve;
// risky waves (near-tie sign decision) redo their batch in fp64 inline.
// =====================================================================
__global__ __launch_bounds__(256)
__attribute__((amdgpu_waves_per_eu(3)))
void qr_fused(const float* __restrict__ x, float* __restrict__ out, int B) {
  const int lane = threadIdx.x & 63;
  const int wave = threadIdx.x >> 6;
  const int b = blockIdx.x * 4 + wave;
  if (b >= B) return;

  const float4* xp = reinterpret_cast<const float4*>(
      x + (size_t)b * (Mrows * Rcols * 2) + (size_t)lane * (Rcols * 2));
  float xr[Rcols], xi[Rcols];   // original A -> becomes Q column-by-column
  float ar[Rcols], ai[Rcols];   // working copy -> R (upper) + reflectors
#pragma unroll
  for (int k = 0; k < Rcols / 2; ++k) {
    float4 t = xp[k];
    xr[2 * k] = t.x;  xi[2 * k] = t.y;
    xr[2 * k + 1] = t.z;  xi[2 * k + 1] = t.w;
  }
#pragma unroll
  for (int j = 0; j < Rcols; ++j) { ar[j] = xr[j]; ai[j] = xi[j]; }

  bool risky = false;

#pragma unroll
  for (int i = 0; i < Rcols; ++i) {
    // ---- clarfg on column i ----
    float cr = ar[i], ci = ai[i];
    float sq = (lane > i) ? fmaf(cr, cr, ci * ci) : 0.0f;
    float xnorm2 = wsum64f_fast(sq);
    float alphr = rdlane(cr, i);
    float alphi = rdlane(ci, i);

    // Near-tie sign decision -> this wave redoes its batch in fp64.
    risky = risky || (fabsf(alphr) < 2e-4f);

    float tr, ti;
    if (xnorm2 == 0.0f && alphi == 0.0f) {
      tr = 0.0f;  ti = 0.0f;  // column reduced; diagonal stays alpha (real)
    } else {
      float nrm = __builtin_amdgcn_sqrtf(
          fmaf(alphr, alphr, fmaf(alphi, alphi, xnorm2)));
      float beta = (alphr >= 0.0f) ? -nrm : nrm;  // -SIGN(nrm, alphr)
      float rb = __builtin_amdgcn_rcpf(beta);
      tr = (beta - alphr) * rb;
      ti = -alphi * rb;
      float dr = alphr - beta, di = alphi;
      float inv = __builtin_amdgcn_rcpf(fmaf(dr, dr, di * di));
      float sr = dr * inv, si = -di * inv;
      if (lane > i) {  // v = x / (alpha - beta), stored below diagonal
        float nr = fmaf(cr, sr, -(ci * si));
        float ni = fmaf(cr, si, ci * sr);
        ar[i] = nr;
        ai[i] = ni;
      }
      if (lane == i) { ar[i] = beta; ai[i] = 0.0f; }  // R diagonal (real)
    }

    // ---- apply H_i^H to trailing columns ----
    float vr = (lane == i) ? 1.0f : ((lane > i) ? ar[i] : 0.0f);
    float vi = (lane == i) ? 0.0f : ((lane > i) ? ai[i] : 0.0f);
    const float ctr = tr, cti = -ti;  // conj(tau)
#pragma unroll
    for (int j = i + 1; j < Rcols; ++j) {
      float pr = fmaf(vr, ar[j], vi * ai[j]);
      float pi = fmaf(vr, ai[j], -(vi * ar[j]));
      pr = wsum64f_fast(pr);
      pi = wsum64f_fast(pi);
      float wr = fmaf(ctr, pr, -(cti * pi));
      float wi = fmaf(ctr, pi, cti * pr);
      ar[j] = fmaf(-wr, vr, fmaf(wi, vi, ar[j]));
      ai[j] = fmaf(-wr, vi, fmaf(-wi, vr, ai[j]));
    }

    // ---- solve column i: q_i = (a_i - sum_{k<i} q_k R[k,i]) / beta_i ----
    // R[k,i] lives in lane k of ar[i]/ai[i]; ar[i]/ai[i] dead afterwards.
    float swr = xr[i], swi = xi[i];
#pragma unroll
    for (int k = 0; k < Rcols; ++k) {
      if (k >= i) break;
      float rr = rdlane(ar[i], k);
      float ri = rdlane(ai[i], k);
      swr = fmaf(-xr[k], rr, fmaf(xi[k], ri, swr));
      swi = fmaf(-xr[k], ri, fmaf(-xi[k], rr, swi));
    }
    float rb = __builtin_amdgcn_rcpf(rdlane(ar[i], i));  // beta_i is real
    xr[i] = swr * rb;
    xi[i] = swi * rb;
  }

  if (risky) {  // wave-uniform branch (~0.26% of waves)
    qr_f64_fused(x, out, b, lane);
    return;
  }

  float4* op = reinterpret_cast<float4*>(
      out + (size_t)b * (Mrows * Rcols * 2) + (size_t)lane * (Rcols * 2));
#pragma unroll
  for (int k = 0; k < Rcols / 2; ++k) {
    op[k] = make_float4(xr[2 * k], xi[2 * k], xr[2 * k + 1], xi[2 * k + 1]);
  }
}

extern "C" void kernel_launch(void* const* d_in, const int* in_sizes, int n_in,
                              void* d_out, int out_size, void* d_ws,
                              size_t ws_size, hipStream_t stream) {
  const float* x = (const float*)d_in[0];
  float* out = (float*)d_out;
  const int B = in_sizes[0] / (Mrows * Rcols * 2);
  dim3 block(256);  // 4 waves -> 4 batch elements per block
  dim3 grid((B + 3) / 4);
  qr_fused<<<grid, block, 0, stream>>>(x, out, B);
}

// Round 8
// 585.563 us; speedup vs baseline: 1.1770x; 1.0933x over previous
//
#include <hip/hip_runtime.h>

// Batched complex QR (Householder, LAPACK clarfg/cgeqr2 convention).
// v9: LAYOUT CHANGE. lane = g*16 + c (g = row-block 0..3, c = column 0..15).
// Each lane holds rows [16g,16g+16) of column c: A-work chunk (32 regs) and
// P chunk (32 regs; P starts as original A and morphs column-by-column into Q
// via the fused triangular-solve push).
//
// Why: rounds 2-8 proved the old row-per-lane layout is pinned at ~370-390us
// by 256 wave-wide dot reductions (6 DPP stages + scalar round-trip each,
// ~12.4k VALU slots/wave vs ~5k semantic). In this layout the 15-i dots of
// step i run CONCURRENTLY across column-lanes as local fmas; cross-lane work
// collapses to 2 within-column fold stages (lane^16, lane^32) per value, and
// w = conj(tau')*p stays a per-lane VGPR (no SGPR ping-pong).
//
// Key mechanics:
//  * u kept UNNORMALIZED (u_i = alpha-beta, tau' = tau/|alpha-beta|^2) so
//    column i is never rewritten; broadcast u via ds_swizzle imm (I<<5)|0x10
//    (src = (l&0x10)|I within each 32-lane half == lane (g,I), g-preserving).
//  * dots zeroed for c<=I (w=0) -> frozen columns never corrupted.
//  * solve push: R[I,c] broadcast from g=0 lanes via ds_bpermute(c*4);
//    Rbc := 0 for c<I (protects finished Q), Rbc := beta-1 for c==I
//    (P - P*(1/beta)*(beta-1) = P/beta -> the uniform update writes q itself).
//  * risky waves (any |Re(alpha_i)| < 2e-4, ~0.26%) redo inline in fp64 with
//    the byte-identical proven v8 path (old layout, loads from x itself).

constexpr int Mrows = 64;
constexpr int Rcols = 16;

typedef int v2i __attribute__((ext_vector_type(2)));

#if defined(__has_builtin)
#if __has_builtin(__builtin_amdgcn_permlane16_swap)
#define USE_PL16 1
#else
#define USE_PL16 0
#endif
#if __has_builtin(__builtin_amdgcn_permlane32_swap)
#define USE_PL32 1
#else
#define USE_PL32 0
#endif
#else
#define USE_PL16 0
#define USE_PL32 0
#endif

__device__ __forceinline__ float rdlane(float v, int srclane) {
  return __int_as_float(__builtin_amdgcn_readlane(__float_as_int(v), srclane));
}

// v[l] + v[l^16]  (column-preserving: (g,c) <-> (g^1,c))
__device__ __forceinline__ float plswap16_addf(float v) {
#if USE_PL16
  v2i r = __builtin_amdgcn_permlane16_swap(__float_as_int(v), __float_as_int(v),
                                           false, false);
  return __int_as_float(r[0]) + __int_as_float(r[1]);
#else
  return v + __shfl_xor(v, 16, 64);
#endif
}

// v[l] + v[l^32]  ((g,c) <-> (g^2,c))
__device__ __forceinline__ float plswap32_addf(float v) {
#if USE_PL32
  v2i r = __builtin_amdgcn_permlane32_swap(__float_as_int(v), __float_as_int(v),
                                           false, false);
  return __int_as_float(r[0]) + __int_as_float(r[1]);
#else
  return v + __shfl_xor(v, 32, 64);
#endif
}

// ---------------- fp64 helpers (proven v8 path, unchanged) ----------------
template <int CTRL, int RM>
__device__ __forceinline__ double dpp_dadd(double v) {
  union { double d; int i[2]; } u, s;
  u.d = v;
  s.i[0] = __builtin_amdgcn_update_dpp(0, u.i[0], CTRL, RM, 0xF, true);
  s.i[1] = __builtin_amdgcn_update_dpp(0, u.i[1], CTRL, RM, 0xF, true);
  return v + s.d;
}

__device__ __forceinline__ double rdlaned(double v, int srclane) {
  union { double d; int i[2]; } u, r;
  u.d = v;
  r.i[0] = __builtin_amdgcn_readlane(u.i[0], srclane);
  r.i[1] = __builtin_amdgcn_readlane(u.i[1], srclane);
  return r.d;
}

__device__ __forceinline__ double wsum64d_fast(double v) {
  v = dpp_dadd<0xB1, 0xF>(v);
  v = dpp_dadd<0x4E, 0xF>(v);
  v = dpp_dadd<0x141, 0xF>(v);
  v = dpp_dadd<0x140, 0xF>(v);
  v = dpp_dadd<0x142, 0xA>(v);
  v = dpp_dadd<0x143, 0xC>(v);
  return rdlaned(v, 63);
}

// =====================================================================
// FP64 redo (rare, ~0.26% of waves): old row-per-lane layout, proven v8.
// =====================================================================
__device__ void qr_f64_fused(const float* __restrict__ x,
                             float* __restrict__ out, int b, int lane) {
  const float4* xp = reinterpret_cast<const float4*>(
      x + (size_t)b * (Mrows * Rcols * 2) + (size_t)lane * (Rcols * 2));
  double xr[Rcols], xi[Rcols], ar[Rcols], ai[Rcols];
#pragma unroll
  for (int k = 0; k < Rcols / 2; ++k) {
    float4 t = xp[k];
    xr[2 * k] = (double)t.x;      xi[2 * k] = (double)t.y;
    xr[2 * k + 1] = (double)t.z;  xi[2 * k + 1] = (double)t.w;
  }
#pragma unroll
  for (int j = 0; j < Rcols; ++j) { ar[j] = xr[j]; ai[j] = xi[j]; }

#pragma unroll
  for (int i = 0; i < Rcols; ++i) {
    double cr = ar[i], ci = ai[i];
    double sq = (lane > i) ? (cr * cr + ci * ci) : 0.0;
    double xnorm2 = wsum64d_fast(sq);
    double alphr = rdlaned(cr, i);
    double alphi = rdlaned(ci, i);

    double tr, ti;
    if (xnorm2 == 0.0 && alphi == 0.0) {
      tr = 0.0;  ti = 0.0;
    } else {
      double nrm = sqrt(alphr * alphr + alphi * alphi + xnorm2);
      double beta = (alphr >= 0.0) ? -nrm : nrm;
      double rb = 1.0 / beta;
      tr = (beta - alphr) * rb;
      ti = -alphi * rb;
      double dr = alphr - beta, di = alphi;
      double inv = 1.0 / (dr * dr + di * di);
      double sr = dr * inv, si = -di * inv;
      if (lane > i) {
        double nr = cr * sr - ci * si;
        double ni = cr * si + ci * sr;
        ar[i] = nr;
        ai[i] = ni;
      }
      if (lane == i) { ar[i] = beta; ai[i] = 0.0; }
    }

    double vr = (lane == i) ? 1.0 : ((lane > i) ? ar[i] : 0.0);
    double vi = (lane == i) ? 0.0 : ((lane > i) ? ai[i] : 0.0);
    const double ctr = tr, cti = -ti;
#pragma unroll
    for (int j = i + 1; j < Rcols; ++j) {
      double pr = fma(vr, ar[j], vi * ai[j]);
      double pi = fma(vr, ai[j], -(vi * ar[j]));
      pr = wsum64d_fast(pr);
      pi = wsum64d_fast(pi);
      double wr = fma(ctr, pr, -(cti * pi));
      double wi = fma(ctr, pi, cti * pr);
      ar[j] = fma(-wr, vr, fma(wi, vi, ar[j]));
      ai[j] = fma(-wr, vi, fma(-wi, vr, ai[j]));
    }

    double swr = xr[i], swi = xi[i];
#pragma unroll
    for (int k = 0; k < Rcols; ++k) {
      if (k >= i) break;
      double rr = rdlaned(ar[i], k);
      double ri = rdlaned(ai[i], k);
      swr = fma(-xr[k], rr, fma(xi[k], ri, swr));
      swi = fma(-xr[k], ri, fma(-xi[k], rr, swi));
    }
    double rbd = 1.0 / rdlaned(ar[i], i);
    xr[i] = swr * rbd;
    xi[i] = swi * rbd;
  }

  float4* op = reinterpret_cast<float4*>(
      out + (size_t)b * (Mrows * Rcols * 2) + (size_t)lane * (Rcols * 2));
#pragma unroll
  for (int k = 0; k < Rcols / 2; ++k) {
    op[k] = make_float4((float)xr[2 * k], (float)xi[2 * k],
                        (float)xr[2 * k + 1], (float)xi[2 * k + 1]);
  }
}

// =====================================================================
// One Householder step in the (g,c) layout. I is a compile-time constant
// (template) so ds_swizzle immediates, readlane indices, and all row/col
// masks are static.
// =====================================================================
template <int I>
__device__ __forceinline__ void qr_step(int lane, float (&Ar)[16], float (&Ai)[16],
                                        float (&Pr)[16], float (&Pi)[16],
                                        int bpaR, bool& risky) {
  const int c = lane & 15;
  const bool g0 = (lane < 16);

  // ---- column norms over rows > I (all columns at once; we use col I) ----
  float ahi = 0.f, alo = 0.f;
#pragma unroll
  for (int m = 0; m < 16; ++m) {
    float s = fmaf(Ar[m], Ar[m], Ai[m] * Ai[m]);
    if (m > I) ahi += s; else alo += s;
  }
  float locn = g0 ? ahi : (ahi + alo);   // g>0 rows are all > I (I<16)
  locn = plswap16_addf(locn);
  locn = plswap32_addf(locn);
  float xnorm2 = rdlane(locn, I);        // lane I = (g=0, c=I)
  float alphr = rdlane(Ar[I], I);        // A[I][I] (diag rows all in g=0)
  float alphi = rdlane(Ai[I], I);
  risky = risky || (fabsf(alphr) < 2e-4f);

  // ---- clarfg scalars (uniform). u unnormalized: u_I = alpha-beta,
  //      tau' = tau/|alpha-beta|^2, apply H^H: a -= conj(tau')(u^H a)u ----
  float ctr, cti, dr, di, beta_s;
  if (xnorm2 == 0.f && alphi == 0.f) {
    ctr = 0.f; cti = 0.f; dr = 0.f; di = 0.f;
    beta_s = alphr;                      // H = I; diagonal stays alpha (real)
  } else {
    float nrm = __builtin_amdgcn_sqrtf(
        fmaf(alphr, alphr, fmaf(alphi, alphi, xnorm2)));
    float beta = (alphr >= 0.f) ? -nrm : nrm;   // -SIGN(nrm, alphr)
    float rbeta = __builtin_amdgcn_rcpf(beta);
    float tr = (beta - alphr) * rbeta;
    float ti = -alphi * rbeta;
    dr = alphr - beta;  di = alphi;
    float inv = __builtin_amdgcn_rcpf(fmaf(dr, dr, di * di));
    ctr = tr * inv;
    cti = -(ti * inv);                   // conj(tau')
    beta_s = beta;
  }
  float rbq = __builtin_amdgcn_rcpf(beta_s);  // 1/R[I,I] for the solve

  // ---- broadcast u chunks: lane (g,c) <- lane (g,I). ds_swizzle BitMode:
  //      src = (l & 0x10) | I within each 32-lane half (g-preserving). ----
  float ur[16], ui[16];
#pragma unroll
  for (int m = 0; m < 16; ++m) {
    ur[m] = __int_as_float(__builtin_amdgcn_ds_swizzle(
        __float_as_int(Ar[m]), (I << 5) | 0x10));
    ui[m] = __int_as_float(__builtin_amdgcn_ds_swizzle(
        __float_as_int(Ai[m]), (I << 5) | 0x10));
  }
  // fixups (g==0 receivers only): rows < I -> 0, row I -> (dr,di)
#pragma unroll
  for (int m = 0; m < I; ++m) {
    ur[m] = g0 ? 0.f : ur[m];
    ui[m] = g0 ? 0.f : ui[m];
  }
  ur[I] = g0 ? dr : ur[I];
  ui[I] = g0 ? di : ui[I];

  // ---- p = u^H a_c (local fma + 2 fold stages); zero for c <= I ----
  float pr = 0.f, pi = 0.f;
#pragma unroll
  for (int m = 0; m < 16; ++m) {
    pr = fmaf(ur[m], Ar[m], fmaf(ui[m], Ai[m], pr));
    pi = fmaf(ur[m], Ai[m], fmaf(-ui[m], Ar[m], pi));
  }
  pr = plswap16_addf(pr);  pr = plswap32_addf(pr);
  pi = plswap16_addf(pi);  pi = plswap32_addf(pi);
  const bool cle = (c <= I);
  pr = cle ? 0.f : pr;
  pi = cle ? 0.f : pi;

  // ---- w = conj(tau')*p (per-lane!); update A ----
  float wr = fmaf(ctr, pr, -(cti * pi));
  float wi = fmaf(ctr, pi, cti * pr);
#pragma unroll
  for (int m = 0; m < 16; ++m) {
    Ar[m] = fmaf(-wr, ur[m], fmaf(wi, ui[m], Ar[m]));
    Ai[m] = fmaf(-wr, ui[m], fmaf(-wi, ur[m], Ai[m]));
  }

  // ---- solve push: q_I = P(c==I)/beta; P_c -= q_I * R[I,c] ----
  // R[I,c] lives at lane (0,c) reg I (post-update) -> bpermute(src=c).
  float rr = __int_as_float(
      __builtin_amdgcn_ds_bpermute(bpaR, __float_as_int(Ar[I])));
  float ri = __int_as_float(
      __builtin_amdgcn_ds_bpermute(bpaR, __float_as_int(Ai[I])));
  const bool ceq = (c == I);
  const bool clt = (c < I);
  rr = ceq ? (beta_s - 1.f) : rr;  // P - P*rbq*(beta-1) = P/beta = q
  rr = clt ? 0.f : rr;             // finished Q columns: no-op
  ri = cle ? 0.f : ri;             // c==I wants ri=0 too

  // broadcast P chunks of column I (reuse ur/ui; sources not yet written)
#pragma unroll
  for (int m = 0; m < 16; ++m) {
    ur[m] = __int_as_float(__builtin_amdgcn_ds_swizzle(
        __float_as_int(Pr[m]), (I << 5) | 0x10));
    ui[m] = __int_as_float(__builtin_amdgcn_ds_swizzle(
        __float_as_int(Pi[m]), (I << 5) | 0x10));
  }
#pragma unroll
  for (int m = 0; m < 16; ++m) {
    float qbr = ur[m] * rbq;
    float qbi = ui[m] * rbq;
    Pr[m] = fmaf(-qbr, rr, fmaf(qbi, ri, Pr[m]));
    Pi[m] = fmaf(-qbr, ri, fmaf(-qbi, rr, Pi[m]));
  }
}

// =====================================================================
// Fused single-dispatch kernel, (g,c) layout.
// =====================================================================
__global__ __launch_bounds__(256)
__attribute__((amdgpu_waves_per_eu(3)))
void qr_fused(const float* __restrict__ x, float* __restrict__ out, int B) {
  const int lane = threadIdx.x & 63;
  const int wave = threadIdx.x >> 6;
  const int b = blockIdx.x * 4 + wave;
  if (b >= B) return;
  const int c = lane & 15;
  const int gbase = lane & 48;     // 16*g
  const int bpaR = c << 2;         // bpermute addr: src lane = c (g=0)

  // load: lane (g,c) <- rows [gbase, gbase+16) of column c
  const float2* xp = reinterpret_cast<const float2*>(x) +
                     (size_t)b * (Mrows * Rcols) + (size_t)gbase * Rcols + c;
  float Ar[16], Ai[16], Pr[16], Pi[16];
#pragma unroll
  for (int m = 0; m < 16; ++m) {
    float2 t = xp[m * Rcols];
    Ar[m] = t.x;  Ai[m] = t.y;
    Pr[m] = t.x;  Pi[m] = t.y;
  }

  bool risky = false;
  qr_step<0>(lane, Ar, Ai, Pr, Pi, bpaR, risky);
  qr_step<1>(lane, Ar, Ai, Pr, Pi, bpaR, risky);
  qr_step<2>(lane, Ar, Ai, Pr, Pi, bpaR, risky);
  qr_step<3>(lane, Ar, Ai, Pr, Pi, bpaR, risky);
  qr_step<4>(lane, Ar, Ai, Pr, Pi, bpaR, risky);
  qr_step<5>(lane, Ar, Ai, Pr, Pi, bpaR, risky);
  qr_step<6>(lane, Ar, Ai, Pr, Pi, bpaR, risky);
  qr_step<7>(lane, Ar, Ai, Pr, Pi, bpaR, risky);
  qr_step<8>(lane, Ar, Ai, Pr, Pi, bpaR, risky);
  qr_step<9>(lane, Ar, Ai, Pr, Pi, bpaR, risky);
  qr_step<10>(lane, Ar, Ai, Pr, Pi, bpaR, risky);
  qr_step<11>(lane, Ar, Ai, Pr, Pi, bpaR, risky);
  qr_step<12>(lane, Ar, Ai, Pr, Pi, bpaR, risky);
  qr_step<13>(lane, Ar, Ai, Pr, Pi, bpaR, risky);
  qr_step<14>(lane, Ar, Ai, Pr, Pi, bpaR, risky);
  qr_step<15>(lane, Ar, Ai, Pr, Pi, bpaR, risky);

  if (risky) {  // wave-uniform (~0.26% of waves): exact fp64 redo
    qr_f64_fused(x, out, b, lane);
    return;
  }

  // store: P now holds Q
  float2* op = reinterpret_cast<float2*>(out) +
               (size_t)b * (Mrows * Rcols) + (size_t)gbase * Rcols + c;
#pragma unroll
  for (int m = 0; m < 16; ++m) {
    op[m * Rcols] = make_float2(Pr[m], Pi[m]);
  }
}

extern "C" void kernel_launch(void* const* d_in, const int* in_sizes, int n_in,
                              void* d_out, int out_size, void* d_ws,
                              size_t ws_size, hipStream_t stream) {
  const float* x = (const float*)d_in[0];
  float* out = (float*)d_out;
  const int B = in_sizes[0] / (Mrows * Rcols * 2);
  dim3 block(256);  // 4 waves -> 4 batch elements per block
  dim3 grid((B + 3) / 4);
  qr_fused<<<grid, block, 0, stream>>>(x, out, B);
}

// Round 10
// 551.921 us; speedup vs baseline: 1.2488x; 1.0610x over previous
//
#include <hip/hip_runtime.h>

// Batched complex QR (Householder, LAPACK clarfg/cgeqr2 convention).
// v10b: v10 with the compile fix — ds_swizzle immediate must be a literal
// constant, so the swizzle helper takes it as a TEMPLATE parameter.
//
// v10 recap (theory unchanged, untested until now):
// lane = g*16 + c (g = row-block 0..3, c = column 0..15); each lane holds
// rows [16g,16g+16) of column c as 8 float2 ROW-PAIRS -> every m-loop fma
// is one v_pk_fma_f32 (halves the ~4.1k-fma semantic core).
//  * incremental norm downdate S -= |R[I,c]|^2 replaces per-step norm loop;
//  * uniform 1/beta folded into broadcast R (rr' = rr*rbq): -32 mul/step;
//  * semantics otherwise identical to v9 (passed): unnormalized u,
//    ds_swizzle (I<<5)|0x10 broadcasts, solve-push with Rbc=beta-1 trick,
//    fp64 inline redo for |Re(alpha_i)| < 2e-4 (~0.26% of waves).

constexpr int Mrows = 64;
constexpr int Rcols = 16;

typedef int v2i __attribute__((ext_vector_type(2)));
typedef float v2f __attribute__((ext_vector_type(2)));

#if defined(__has_builtin)
#if __has_builtin(__builtin_amdgcn_permlane16_swap)
#define USE_PL16 1
#else
#define USE_PL16 0
#endif
#if __has_builtin(__builtin_amdgcn_permlane32_swap)
#define USE_PL32 1
#else
#define USE_PL32 0
#endif
#else
#define USE_PL16 0
#define USE_PL32 0
#endif

__device__ __forceinline__ float rdlane(float v, int srclane) {
  return __int_as_float(__builtin_amdgcn_readlane(__float_as_int(v), srclane));
}

// v[l] + v[l^16]  (column-preserving: (g,c) <-> (g^1,c))
__device__ __forceinline__ float plswap16_addf(float v) {
#if USE_PL16
  v2i r = __builtin_amdgcn_permlane16_swap(__float_as_int(v), __float_as_int(v),
                                           false, false);
  return __int_as_float(r[0]) + __int_as_float(r[1]);
#else
  return v + __shfl_xor(v, 16, 64);
#endif
}

// v[l] + v[l^32]  ((g,c) <-> (g^2,c))
__device__ __forceinline__ float plswap32_addf(float v) {
#if USE_PL32
  v2i r = __builtin_amdgcn_permlane32_swap(__float_as_int(v), __float_as_int(v),
                                           false, false);
  return __int_as_float(r[0]) + __int_as_float(r[1]);
#else
  return v + __shfl_xor(v, 32, 64);
#endif
}

// Packed fp32 fma: one v_pk_fma_f32 per call.
__device__ __forceinline__ v2f pkfma(v2f a, v2f b, v2f c) {
#if defined(__has_builtin) && __has_builtin(__builtin_elementwise_fma)
  return __builtin_elementwise_fma(a, b, c);
#else
  v2f r;
  r[0] = fmaf(a[0], b[0], c[0]);
  r[1] = fmaf(a[1], b[1], c[1]);
  return r;
#endif
}

__device__ __forceinline__ v2f splat2(float s) { v2f r; r[0] = s; r[1] = s; return r; }

// ds_swizzle with compile-time immediate (builtin requires a literal const).
template <int IMM>
__device__ __forceinline__ float dswz(float v) {
  return __int_as_float(__builtin_amdgcn_ds_swizzle(__float_as_int(v), IMM));
}

// ---------------- fp64 helpers (proven v8/v9 path, unchanged) ----------------
template <int CTRL, int RM>
__device__ __forceinline__ double dpp_dadd(double v) {
  union { double d; int i[2]; } u, s;
  u.d = v;
  s.i[0] = __builtin_amdgcn_update_dpp(0, u.i[0], CTRL, RM, 0xF, true);
  s.i[1] = __builtin_amdgcn_update_dpp(0, u.i[1], CTRL, RM, 0xF, true);
  return v + s.d;
}

__device__ __forceinline__ double rdlaned(double v, int srclane) {
  union { double d; int i[2]; } u, r;
  u.d = v;
  r.i[0] = __builtin_amdgcn_readlane(u.i[0], srclane);
  r.i[1] = __builtin_amdgcn_readlane(u.i[1], srclane);
  return r.d;
}

__device__ __forceinline__ double wsum64d_fast(double v) {
  v = dpp_dadd<0xB1, 0xF>(v);
  v = dpp_dadd<0x4E, 0xF>(v);
  v = dpp_dadd<0x141, 0xF>(v);
  v = dpp_dadd<0x140, 0xF>(v);
  v = dpp_dadd<0x142, 0xA>(v);
  v = dpp_dadd<0x143, 0xC>(v);
  return rdlaned(v, 63);
}

// =====================================================================
// FP64 redo (rare, ~0.26% of waves): old row-per-lane layout, proven.
// =====================================================================
__device__ void qr_f64_fused(const float* __restrict__ x,
                             float* __restrict__ out, int b, int lane) {
  const float4* xp = reinterpret_cast<const float4*>(
      x + (size_t)b * (Mrows * Rcols * 2) + (size_t)lane * (Rcols * 2));
  double xr[Rcols], xi[Rcols], ar[Rcols], ai[Rcols];
#pragma unroll
  for (int k = 0; k < Rcols / 2; ++k) {
    float4 t = xp[k];
    xr[2 * k] = (double)t.x;      xi[2 * k] = (double)t.y;
    xr[2 * k + 1] = (double)t.z;  xi[2 * k + 1] = (double)t.w;
  }
#pragma unroll
  for (int j = 0; j < Rcols; ++j) { ar[j] = xr[j]; ai[j] = xi[j]; }

#pragma unroll
  for (int i = 0; i < Rcols; ++i) {
    double cr = ar[i], ci = ai[i];
    double sq = (lane > i) ? (cr * cr + ci * ci) : 0.0;
    double xnorm2 = wsum64d_fast(sq);
    double alphr = rdlaned(cr, i);
    double alphi = rdlaned(ci, i);

    double tr, ti;
    if (xnorm2 == 0.0 && alphi == 0.0) {
      tr = 0.0;  ti = 0.0;
    } else {
      double nrm = sqrt(alphr * alphr + alphi * alphi + xnorm2);
      double beta = (alphr >= 0.0) ? -nrm : nrm;
      double rb = 1.0 / beta;
      tr = (beta - alphr) * rb;
      ti = -alphi * rb;
      double dr = alphr - beta, di = alphi;
      double inv = 1.0 / (dr * dr + di * di);
      double sr = dr * inv, si = -di * inv;
      if (lane > i) {
        double nr = cr * sr - ci * si;
        double ni = cr * si + ci * sr;
        ar[i] = nr;
        ai[i] = ni;
      }
      if (lane == i) { ar[i] = beta; ai[i] = 0.0; }
    }

    double vr = (lane == i) ? 1.0 : ((lane > i) ? ar[i] : 0.0);
    double vi = (lane == i) ? 0.0 : ((lane > i) ? ai[i] : 0.0);
    const double ctr = tr, cti = -ti;
#pragma unroll
    for (int j = i + 1; j < Rcols; ++j) {
      double pr = fma(vr, ar[j], vi * ai[j]);
      double pi = fma(vr, ai[j], -(vi * ar[j]));
      pr = wsum64d_fast(pr);
      pi = wsum64d_fast(pi);
      double wr = fma(ctr, pr, -(cti * pi));
      double wi = fma(ctr, pi, cti * pr);
      ar[j] = fma(-wr, vr, fma(wi, vi, ar[j]));
      ai[j] = fma(-wr, vi, fma(-wi, vr, ai[j]));
    }

    double swr = xr[i], swi = xi[i];
#pragma unroll
    for (int k = 0; k < Rcols; ++k) {
      if (k >= i) break;
      double rr = rdlaned(ar[i], k);
      double ri = rdlaned(ai[i], k);
      swr = fma(-xr[k], rr, fma(xi[k], ri, swr));
      swi = fma(-xr[k], ri, fma(-xi[k], rr, swi));
    }
    double rbd = 1.0 / rdlaned(ar[i], i);
    xr[i] = swr * rbd;
    xi[i] = swi * rbd;
  }

  float4* op = reinterpret_cast<float4*>(
      out + (size_t)b * (Mrows * Rcols * 2) + (size_t)lane * (Rcols * 2));
#pragma unroll
  for (int k = 0; k < Rcols / 2; ++k) {
    op[k] = make_float4((float)xr[2 * k], (float)xi[2 * k],
                        (float)xr[2 * k + 1], (float)xi[2 * k + 1]);
  }
}

// =====================================================================
// One Householder step, (g,c) layout, row-pair packed. I compile-time.
// S = per-lane running norm^2 of own column over rows >= I (downdated).
// =====================================================================
template <int I>
__device__ __forceinline__ void qr_step(int lane,
                                        v2f (&Ar2)[8], v2f (&Ai2)[8],
                                        v2f (&Pr2)[8], v2f (&Pi2)[8],
                                        float& S, int bpaR, bool& risky) {
  const int c = lane & 15;
  const bool g0 = (lane < 16);
  constexpr int IH = I / 2;
  constexpr int ILo = I % 2;
  constexpr int SWZ = (I << 5) | 0x10;  // src = (l & 0x10) | I, g-preserving
  const v2f z2 = splat2(0.f);

  // ---- alpha and trailing norm (from downdated S) ----
  float alphr = rdlane(Ar2[IH][ILo], I);  // A[I][I]: lane I=(g0,c=I), m=I
  float alphi = rdlane(Ai2[IH][ILo], I);
  float SI = rdlane(S, I);                // col-I norm^2 over rows >= I
  float xnorm2 = fmaxf(SI - fmaf(alphr, alphr, alphi * alphi), 0.f);
  risky = risky || (fabsf(alphr) < 2e-4f);

  // ---- clarfg scalars (uniform). u unnormalized: u_I = alpha-beta,
  //      tau' = tau/|alpha-beta|^2; apply H^H: a -= conj(tau')(u^H a)u ----
  float ctr, cti, dr, di, beta_s;
  if (xnorm2 == 0.f && alphi == 0.f) {
    ctr = 0.f; cti = 0.f; dr = 0.f; di = 0.f;
    beta_s = alphr;                       // H = I; diagonal stays alpha (real)
  } else {
    float nrm = __builtin_amdgcn_sqrtf(
        fmaf(alphr, alphr, fmaf(alphi, alphi, xnorm2)));
    float beta = (alphr >= 0.f) ? -nrm : nrm;   // -SIGN(nrm, alphr)
    float rbeta = __builtin_amdgcn_rcpf(beta);
    float tr = (beta - alphr) * rbeta;
    float ti = -alphi * rbeta;
    dr = alphr - beta;  di = alphi;
    float inv = __builtin_amdgcn_rcpf(fmaf(dr, dr, di * di));
    ctr = tr * inv;
    cti = -(ti * inv);                    // conj(tau')
    beta_s = beta;
  }
  float rbq = __builtin_amdgcn_rcpf(beta_s);  // 1/R[I,I] for the solve

  // ---- broadcast u: lane (g,c) <- lane (g,I); swizzle per 32-bit half ----
  v2f ur2[8], ui2[8];
#pragma unroll
  for (int h = 0; h < 8; ++h) {
    v2f t, s;
    t[0] = dswz<SWZ>(Ar2[h][0]);
    t[1] = dswz<SWZ>(Ar2[h][1]);
    s[0] = dswz<SWZ>(Ai2[h][0]);
    s[1] = dswz<SWZ>(Ai2[h][1]);
    ur2[h] = t;  ui2[h] = s;
  }
  // fixups (g==0 receivers only): rows < I -> 0, row I -> (dr,di)
#pragma unroll
  for (int h = 0; h < IH; ++h) {          // pairs fully below row I
    ur2[h] = g0 ? z2 : ur2[h];
    ui2[h] = g0 ? z2 : ui2[h];
  }
  if constexpr (ILo == 1) {               // pair IH = (I-1, I)
    ur2[IH][0] = g0 ? 0.f : ur2[IH][0];
    ui2[IH][0] = g0 ? 0.f : ui2[IH][0];
    ur2[IH][1] = g0 ? dr : ur2[IH][1];
    ui2[IH][1] = g0 ? di : ui2[IH][1];
  } else {                                // pair IH = (I, I+1)
    ur2[IH][0] = g0 ? dr : ur2[IH][0];
    ui2[IH][0] = g0 ? di : ui2[IH][0];
  }

  // ---- p = u^H a_c (packed fma + 2 fold stages); zero for c <= I ----
  v2f prv = z2, piv = z2;
#pragma unroll
  for (int h = 0; h < 8; ++h) {
    prv = pkfma(ur2[h], Ar2[h], pkfma(ui2[h], Ai2[h], prv));
    piv = pkfma(ur2[h], Ai2[h], pkfma(-ui2[h], Ar2[h], piv));
  }
  float pr = prv[0] + prv[1];
  float pi = piv[0] + piv[1];
  pr = plswap16_addf(pr);  pr = plswap32_addf(pr);
  pi = plswap16_addf(pi);  pi = plswap32_addf(pi);
  const bool cle = (c <= I);
  pr = cle ? 0.f : pr;
  pi = cle ? 0.f : pi;

  // ---- w = conj(tau')*p (per-lane); update A (packed) ----
  float wr = fmaf(ctr, pr, -(cti * pi));
  float wi = fmaf(ctr, pi, cti * pr);
  const v2f wrv = splat2(wr), wiv = splat2(wi);
#pragma unroll
  for (int h = 0; h < 8; ++h) {
    Ar2[h] = pkfma(-wrv, ur2[h], pkfma(wiv, ui2[h], Ar2[h]));
    Ai2[h] = pkfma(-wrv, ui2[h], pkfma(-wiv, ur2[h], Ai2[h]));
  }

  // ---- solve push: q_I = P(c==I)/beta; P_c -= q_I * R[I,c] ----
  // R[I,c] at lane (0,c), reg (IH,ILo) post-update -> bpermute(src=c).
  float rr = __int_as_float(
      __builtin_amdgcn_ds_bpermute(bpaR, __float_as_int(Ar2[IH][ILo])));
  float ri = __int_as_float(
      __builtin_amdgcn_ds_bpermute(bpaR, __float_as_int(Ai2[IH][ILo])));
  const bool ceq = (c == I);
  const bool clt = (c < I);
  rr = ceq ? (beta_s - 1.f) : rr;  // P - P*rbq*(beta-1) = P/beta = q
  rr = clt ? 0.f : rr;             // finished Q columns: no-op
  ri = cle ? 0.f : ri;             // c==I wants ri=0 too

  // norm downdate for next step: S(rows>=I+1) = S(rows>=I) - |R[I,c]|^2.
  // (c<=I entries become garbage; never read again — future steps read c>I.)
  S = S - fmaf(rr, rr, ri * ri);

  // fold uniform 1/beta into the broadcast R value (replaces 32 muls)
  const v2f rrv = splat2(rr * rbq), riv = splat2(ri * rbq);

  // broadcast P chunks of column I
  v2f br2[8], bi2[8];
#pragma unroll
  for (int h = 0; h < 8; ++h) {
    v2f t, s;
    t[0] = dswz<SWZ>(Pr2[h][0]);
    t[1] = dswz<SWZ>(Pr2[h][1]);
    s[0] = dswz<SWZ>(Pi2[h][0]);
    s[1] = dswz<SWZ>(Pi2[h][1]);
    br2[h] = t;  bi2[h] = s;
  }
#pragma unroll
  for (int h = 0; h < 8; ++h) {
    Pr2[h] = pkfma(-br2[h], rrv, pkfma(bi2[h], riv, Pr2[h]));
    Pi2[h] = pkfma(-br2[h], riv, pkfma(-bi2[h], rrv, Pi2[h]));
  }
}

// =====================================================================
// Fused single-dispatch kernel, (g,c) layout, packed row-pairs.
// =====================================================================
__global__ __launch_bounds__(256)
__attribute__((amdgpu_waves_per_eu(3)))
void qr_fused(const float* __restrict__ x, float* __restrict__ out, int B) {
  const int lane = threadIdx.x & 63;
  const int wave = threadIdx.x >> 6;
  const int b = blockIdx.x * 4 + wave;
  if (b >= B) return;
  const int c = lane & 15;
  const int gbase = lane & 48;     // 16*g
  const int bpaR = c << 2;         // bpermute addr: src lane = c (g=0)

  // load: lane (g,c) <- rows [gbase, gbase+16) of column c (row-pair packed)
  const float2* xp = reinterpret_cast<const float2*>(x) +
                     (size_t)b * (Mrows * Rcols) + (size_t)gbase * Rcols + c;
  v2f Ar2[8], Ai2[8], Pr2[8], Pi2[8];
#pragma unroll
  for (int h = 0; h < 8; ++h) {
    float2 t0 = xp[(2 * h) * Rcols];
    float2 t1 = xp[(2 * h + 1) * Rcols];
    v2f r, s;
    r[0] = t0.x;  r[1] = t1.x;
    s[0] = t0.y;  s[1] = t1.y;
    Ar2[h] = r;  Ai2[h] = s;
    Pr2[h] = r;  Pi2[h] = s;
  }

  // initial per-column norm^2 (rows >= 0), folded within the column
  v2f s2 = splat2(0.f);
#pragma unroll
  for (int h = 0; h < 8; ++h) {
    s2 = pkfma(Ar2[h], Ar2[h], pkfma(Ai2[h], Ai2[h], s2));
  }
  float S = s2[0] + s2[1];
  S = plswap16_addf(S);
  S = plswap32_addf(S);

  bool risky = false;
  qr_step<0>(lane, Ar2, Ai2, Pr2, Pi2, S, bpaR, risky);
  qr_step<1>(lane, Ar2, Ai2, Pr2, Pi2, S, bpaR, risky);
  qr_step<2>(lane, Ar2, Ai2, Pr2, Pi2, S, bpaR, risky);
  qr_step<3>(lane, Ar2, Ai2, Pr2, Pi2, S, bpaR, risky);
  qr_step<4>(lane, Ar2, Ai2, Pr2, Pi2, S, bpaR, risky);
  qr_step<5>(lane, Ar2, Ai2, Pr2, Pi2, S, bpaR, risky);
  qr_step<6>(lane, Ar2, Ai2, Pr2, Pi2, S, bpaR, risky);
  qr_step<7>(lane, Ar2, Ai2, Pr2, Pi2, S, bpaR, risky);
  qr_step<8>(lane, Ar2, Ai2, Pr2, Pi2, S, bpaR, risky);
  qr_step<9>(lane, Ar2, Ai2, Pr2, Pi2, S, bpaR, risky);
  qr_step<10>(lane, Ar2, Ai2, Pr2, Pi2, S, bpaR, risky);
  qr_step<11>(lane, Ar2, Ai2, Pr2, Pi2, S, bpaR, risky);
  qr_step<12>(lane, Ar2, Ai2, Pr2, Pi2, S, bpaR, risky);
  qr_step<13>(lane, Ar2, Ai2, Pr2, Pi2, S, bpaR, risky);
  qr_step<14>(lane, Ar2, Ai2, Pr2, Pi2, S, bpaR, risky);
  qr_step<15>(lane, Ar2, Ai2, Pr2, Pi2, S, bpaR, risky);

  if (risky) {  // wave-uniform (~0.26% of waves): exact fp64 redo
    qr_f64_fused(x, out, b, lane);
    return;
  }

  // store: P now holds Q
  float2* op = reinterpret_cast<float2*>(out) +
               (size_t)b * (Mrows * Rcols) + (size_t)gbase * Rcols + c;
#pragma unroll
  for (int h = 0; h < 8; ++h) {
    op[(2 * h) * Rcols] = make_float2(Pr2[h][0], Pi2[h][0]);
    op[(2 * h + 1) * Rcols] = make_float2(Pr2[h][1], Pi2[h][1]);
  }
}

extern "C" void kernel_launch(void* const* d_in, const int* in_sizes, int n_in,
                              void* d_out, int out_size, void* d_ws,
                              size_t ws_size, hipStream_t stream) {
  const float* x = (const float*)d_in[0];
  float* out = (float*)d_out;
  const int B = in_sizes[0] / (Mrows * Rcols * 2);
  dim3 block(256);  // 4 waves -> 4 batch elements per block
  dim3 grid((B + 3) / 4);
  qr_fused<<<grid, block, 0, stream>>>(x, out, B);
}